// Round 1
// baseline (33202.240 us; speedup 1.0000x reference)
//
#include <hip/hip_runtime.h>
#include <hip/hip_bf16.h>

// Problem constants
#define BB 256   // batch
#define TT 1024  // seq len
#define FF 64    // features
#define EE 256   // hidden

typedef _Float16 f16x8 __attribute__((ext_vector_type(8)));
typedef float    f32x4 __attribute__((ext_vector_type(4)));

__device__ __forceinline__ float fsig(float v) {
    // 1/(1+exp(-v)) via exp2/rcp (≈1 ulp each; tolerance is ~8e-3)
    return __builtin_amdgcn_rcpf(1.f + __builtin_amdgcn_exp2f(v * -1.44269504089f));
}
__device__ __forceinline__ float ftanhf(float v) {
    // tanh(v) = 1 - 2/(exp(2v)+1)
    return 1.f - 2.f * __builtin_amdgcn_rcpf(1.f + __builtin_amdgcn_exp2f(v * 2.88539008178f));
}

// ---------------------------------------------------------------------------
// Setup: fuse decoder weights (W' = dec_Whh + dec_Wih @ Wd,
// b' = dec_bih + dec_bhh + dec_Wih @ bd), convert all weights to fp16.
// grid = 1024 blocks (one per gate row j), 256 threads (one per e column).
// ---------------------------------------------------------------------------
__global__ void setup_kernel(const float* __restrict__ eWih, const float* __restrict__ eWhh,
                             const float* __restrict__ ebih, const float* __restrict__ ebhh,
                             const float* __restrict__ dWih, const float* __restrict__ dWhh,
                             const float* __restrict__ dbih, const float* __restrict__ dbhh,
                             const float* __restrict__ Wd,   const float* __restrict__ bd,
                             _Float16* __restrict__ whh16, _Float16* __restrict__ wp16,
                             _Float16* __restrict__ wih16, _Float16* __restrict__ wd16,
                             float* __restrict__ biasE, float* __restrict__ biasD)
{
    const int j = blockIdx.x;   // 0..1023 gate row
    const int e = threadIdx.x;  // 0..255 hidden col
    __shared__ float lih[FF];
    if (e < FF) lih[e] = dWih[j * FF + e];
    __syncthreads();

    float acc = dWhh[j * EE + e];
#pragma unroll 8
    for (int f = 0; f < FF; ++f) acc += lih[f] * Wd[f * EE + e];  // (Wih@Wd)[j][e]
    wp16[j * EE + e]  = (_Float16)acc;
    whh16[j * EE + e] = (_Float16)eWhh[j * EE + e];
    if (e < FF) wih16[j * FF + e] = (_Float16)eWih[j * FF + e];
    if (j < FF) wd16[j * EE + e]  = (_Float16)Wd[j * EE + e];
    if (e == 0) {
        float s = dbih[j] + dbhh[j];
        for (int f = 0; f < FF; ++f) s += lih[f] * bd[f];
        biasD[j] = s;
        biasE[j] = ebih[j] + ebhh[j];
    }
}

// ---------------------------------------------------------------------------
// Main persistent kernel: 16 blocks x 1024 threads. Block g owns batch rows
// [16g, 16g+16). Wave w (0..15) owns hidden cols e in [16w, 16w+16) for all
// four gates (Ntiles {g*16 + w*... -> j = gate*256 + w*16 + p}).
// Per step: gates(16b x 64j slice per wave) = h(16x256)@W^T via
// mfma_f32_16x16x32_f16, activations in f32, h exchanged via swizzled LDS.
// ---------------------------------------------------------------------------
__global__ __launch_bounds__(1024, 4) void lstm_main(
    const float* __restrict__ x,
    const _Float16* __restrict__ whhG,   // enc Whh fp16 [1024][256]
    const _Float16* __restrict__ wpG,    // fused dec W' fp16 [1024][256]
    const _Float16* __restrict__ wihG,   // enc Wih fp16 [1024][64]
    const _Float16* __restrict__ wdG,    // Wd fp16 [64][256]
    const float* __restrict__ biasE,     // enc bih+bhh [1024]
    const float* __restrict__ biasD,     // fused dec bias [1024]
    const float* __restrict__ bdp,       // bd [64] (f32, raw input)
    float* __restrict__ out)             // [T][B][F] f32
{
    const int tid  = threadIdx.x;
    const int w    = tid >> 6;    // wave 0..15
    const int lane = tid & 63;
    const int p    = lane & 15;   // A-row / B-col / D-col index
    const int q    = lane >> 4;   // k-group; D rows = q*4+r
    const int b0   = blockIdx.x << 4;

    // double-buffered h tile [16 rows][256 cols] fp16, XOR-swizzled:
    // half-index = row*256 + (col ^ ((row&7)<<3))  -> ~2-way banks on b128 reads
    __shared__ _Float16 hbuf[2][16 * 256];

    // --- persistent weight fragments (encoder Whh now; reloaded as W' later) ---
    f16x8 wgt[4][8];   // [gate][kslice], B-frag: W[j][k0..k0+7], j = g*256+w*16+p
    f16x8 wih[4][2];
    float be[4], bp[4];
#pragma unroll
    for (int g = 0; g < 4; ++g) {
        const int j = g * 256 + w * 16 + p;
#pragma unroll
        for (int ks = 0; ks < 8; ++ks)
            wgt[g][ks] = *(const f16x8*)(whhG + j * EE + ks * 32 + q * 8);
        wih[g][0] = *(const f16x8*)(wihG + j * FF + q * 8);
        wih[g][1] = *(const f16x8*)(wihG + j * FF + 32 + q * 8);
        be[g] = biasE[j];
        bp[g] = biasD[j];
    }

    f16x8 ha[8] = {};                 // A-frags of current h (h0 = 0)
    f32x4 cst = {0.f, 0.f, 0.f, 0.f}; // c state, rows q*4+r, col w*16+p

    // x row base for this lane's A-row (row = p)
    const float* xb = x + (size_t)(b0 + p) * TT * FF;
    f32x4 r0 = *(const f32x4*)(xb + q * 8);
    f32x4 r1 = *(const f32x4*)(xb + q * 8 + 4);
    f32x4 r2 = *(const f32x4*)(xb + 32 + q * 8);
    f32x4 r3 = *(const f32x4*)(xb + 32 + q * 8 + 4);

    // ================= encoder: 1024 steps =================
    for (int t = 0; t < TT; ++t) {
        f16x8 xa0, xa1;
#pragma unroll
        for (int j2 = 0; j2 < 4; ++j2) {
            xa0[j2]     = (_Float16)r0[j2];
            xa0[j2 + 4] = (_Float16)r1[j2];
            xa1[j2]     = (_Float16)r2[j2];
            xa1[j2 + 4] = (_Float16)r3[j2];
        }
        f32x4 a0 = {be[0], be[0], be[0], be[0]};
        f32x4 a1 = {be[1], be[1], be[1], be[1]};
        f32x4 a2 = {be[2], be[2], be[2], be[2]};
        f32x4 a3 = {be[3], be[3], be[3], be[3]};
#pragma unroll
        for (int ks = 0; ks < 8; ++ks) {
            a0 = __builtin_amdgcn_mfma_f32_16x16x32_f16(ha[ks], wgt[0][ks], a0, 0, 0, 0);
            a1 = __builtin_amdgcn_mfma_f32_16x16x32_f16(ha[ks], wgt[1][ks], a1, 0, 0, 0);
            a2 = __builtin_amdgcn_mfma_f32_16x16x32_f16(ha[ks], wgt[2][ks], a2, 0, 0, 0);
            a3 = __builtin_amdgcn_mfma_f32_16x16x32_f16(ha[ks], wgt[3][ks], a3, 0, 0, 0);
        }
        a0 = __builtin_amdgcn_mfma_f32_16x16x32_f16(xa0, wih[0][0], a0, 0, 0, 0);
        a0 = __builtin_amdgcn_mfma_f32_16x16x32_f16(xa1, wih[0][1], a0, 0, 0, 0);
        a1 = __builtin_amdgcn_mfma_f32_16x16x32_f16(xa0, wih[1][0], a1, 0, 0, 0);
        a1 = __builtin_amdgcn_mfma_f32_16x16x32_f16(xa1, wih[1][1], a1, 0, 0, 0);
        a2 = __builtin_amdgcn_mfma_f32_16x16x32_f16(xa0, wih[2][0], a2, 0, 0, 0);
        a2 = __builtin_amdgcn_mfma_f32_16x16x32_f16(xa1, wih[2][1], a2, 0, 0, 0);
        a3 = __builtin_amdgcn_mfma_f32_16x16x32_f16(xa0, wih[3][0], a3, 0, 0, 0);
        a3 = __builtin_amdgcn_mfma_f32_16x16x32_f16(xa1, wih[3][1], a3, 0, 0, 0);

        // prefetch x_{t+1} (latency hides under activations + barrier)
        if (t + 1 < TT) {
            const float* xn = xb + (size_t)(t + 1) * FF;
            r0 = *(const f32x4*)(xn + q * 8);
            r1 = *(const f32x4*)(xn + q * 8 + 4);
            r2 = *(const f32x4*)(xn + 32 + q * 8);
            r3 = *(const f32x4*)(xn + 32 + q * 8 + 4);
        }

        // activations: lane holds gates for (b = q*4+r, e = w*16+p)
#pragma unroll
        for (int r = 0; r < 4; ++r) {
            float iv = fsig(a0[r]);
            float fv = fsig(a1[r]);
            float gv = ftanhf(a2[r]);
            float ov = fsig(a3[r]);
            float c  = fv * cst[r] + iv * gv;
            cst[r]   = c;
            float hv = ov * ftanhf(c);
            const int row = q * 4 + r;
            hbuf[t & 1][row * 256 + ((w * 16 + p) ^ ((row & 7) << 3))] = (_Float16)hv;
        }
        __syncthreads();
        {
            const _Float16* hb = hbuf[t & 1];
#pragma unroll
            for (int ks = 0; ks < 8; ++ks)
                ha[ks] = *(const f16x8*)(hb + p * 256 + ((ks * 32 + q * 8) ^ ((p & 7) << 3)));
        }
    }

    // ================= decoder: reload fused W', load Wd =================
#pragma unroll
    for (int g = 0; g < 4; ++g) {
        const int j = g * 256 + w * 16 + p;
#pragma unroll
        for (int ks = 0; ks < 8; ++ks)
            wgt[g][ks] = *(const f16x8*)(wpG + j * EE + ks * 32 + q * 8);
    }
    f16x8 wd[8] = {};
    float bdv = 0.f;
    if (w < 4) {  // waves 0..3 own output cols fo = w*16+p (one per SIMD: balanced)
#pragma unroll
        for (int ks = 0; ks < 8; ++ks)
            wd[ks] = *(const f16x8*)(wdG + (w * 16 + p) * EE + ks * 32 + q * 8);
        bdv = bdp[w * 16 + p];
    }

    // out[t] = h_t @ Wd^T + bd with h_0 = encoder final h (already in ha)
    for (int t = 0; t < TT; ++t) {
        if (w < 4) {
            f32x4 oa = {bdv, bdv, bdv, bdv};
#pragma unroll
            for (int ks = 0; ks < 8; ++ks)
                oa = __builtin_amdgcn_mfma_f32_16x16x32_f16(ha[ks], wd[ks], oa, 0, 0, 0);
            float* ob = out + (size_t)t * (BB * FF) + (size_t)b0 * FF + (w * 16 + p);
#pragma unroll
            for (int r = 0; r < 4; ++r)
                ob[(q * 4 + r) * FF] = oa[r];
        }
        if (t == TT - 1) break;

        f32x4 a0 = {bp[0], bp[0], bp[0], bp[0]};
        f32x4 a1 = {bp[1], bp[1], bp[1], bp[1]};
        f32x4 a2 = {bp[2], bp[2], bp[2], bp[2]};
        f32x4 a3 = {bp[3], bp[3], bp[3], bp[3]};
#pragma unroll
        for (int ks = 0; ks < 8; ++ks) {
            a0 = __builtin_amdgcn_mfma_f32_16x16x32_f16(ha[ks], wgt[0][ks], a0, 0, 0, 0);
            a1 = __builtin_amdgcn_mfma_f32_16x16x32_f16(ha[ks], wgt[1][ks], a1, 0, 0, 0);
            a2 = __builtin_amdgcn_mfma_f32_16x16x32_f16(ha[ks], wgt[2][ks], a2, 0, 0, 0);
            a3 = __builtin_amdgcn_mfma_f32_16x16x32_f16(ha[ks], wgt[3][ks], a3, 0, 0, 0);
        }
#pragma unroll
        for (int r = 0; r < 4; ++r) {
            float iv = fsig(a0[r]);
            float fv = fsig(a1[r]);
            float gv = ftanhf(a2[r]);
            float ov = fsig(a3[r]);
            float c  = fv * cst[r] + iv * gv;
            cst[r]   = c;
            float hv = ov * ftanhf(c);
            const int row = q * 4 + r;
            hbuf[t & 1][row * 256 + ((w * 16 + p) ^ ((row & 7) << 3))] = (_Float16)hv;
        }
        __syncthreads();
        {
            const _Float16* hb = hbuf[t & 1];
#pragma unroll
            for (int ks = 0; ks < 8; ++ks)
                ha[ks] = *(const f16x8*)(hb + p * 256 + ((ks * 32 + q * 8) ^ ((p & 7) << 3)));
        }
    }
}

// ---------------------------------------------------------------------------
extern "C" void kernel_launch(void* const* d_in, const int* in_sizes, int n_in,
                              void* d_out, int out_size, void* d_ws, size_t ws_size,
                              hipStream_t stream) {
    const float* x    = (const float*)d_in[0];
    const float* eWih = (const float*)d_in[1];
    const float* eWhh = (const float*)d_in[2];
    const float* ebih = (const float*)d_in[3];
    const float* ebhh = (const float*)d_in[4];
    const float* dWih = (const float*)d_in[5];
    const float* dWhh = (const float*)d_in[6];
    const float* dbih = (const float*)d_in[7];
    const float* dbhh = (const float*)d_in[8];
    const float* Wd   = (const float*)d_in[9];
    const float* bd   = (const float*)d_in[10];

    // workspace layout (fp16 weights + f32 biases), ~1.17 MB total
    char* ws = (char*)d_ws;
    _Float16* whh16 = (_Float16*)(ws + 0);         // 1024*256*2 = 524288
    _Float16* wp16  = (_Float16*)(ws + 524288);    // 524288
    _Float16* wih16 = (_Float16*)(ws + 1048576);   // 1024*64*2 = 131072
    _Float16* wd16  = (_Float16*)(ws + 1179648);   // 64*256*2 = 32768
    float*    biasE = (float*)(ws + 1212416);      // 4096
    float*    biasD = (float*)(ws + 1216512);      // 4096

    hipLaunchKernelGGL(setup_kernel, dim3(1024), dim3(256), 0, stream,
                       eWih, eWhh, ebih, ebhh, dWih, dWhh, dbih, dbhh, Wd, bd,
                       whh16, wp16, wih16, wd16, biasE, biasD);

    hipLaunchKernelGGL(lstm_main, dim3(16), dim3(1024), 0, stream,
                       x, whh16, wp16, wih16, wd16, biasE, biasD, bd,
                       (float*)d_out);
}

// Round 3
// 11659.567 us; speedup vs baseline: 2.8476x; 2.8476x over previous
//
#include <hip/hip_runtime.h>
#include <hip/hip_bf16.h>

#define BB 256   // batch
#define TT 1024  // seq len
#define FF 64    // features
#define EE 256   // hidden

typedef _Float16 f16x8 __attribute__((ext_vector_type(8)));
typedef float    f32x4 __attribute__((ext_vector_type(4)));

#define MFMA(a,b,c) __builtin_amdgcn_mfma_f32_16x16x32_f16((a),(b),(c),0,0,0)

__device__ __forceinline__ float fsig(float v) {
    return __builtin_amdgcn_rcpf(1.f + __builtin_amdgcn_exp2f(v * -1.44269504089f));
}
__device__ __forceinline__ float ftanhf(float v) {
    return 1.f - 2.f * __builtin_amdgcn_rcpf(1.f + __builtin_amdgcn_exp2f(v * 2.88539008178f));
}
__device__ __forceinline__ f16x8 cvt2(f32x4 a, f32x4 b) {
    f16x8 r;
#pragma unroll
    for (int e = 0; e < 4; ++e) { r[e] = (_Float16)a[e]; r[4+e] = (_Float16)b[e]; }
    return r;
}
__device__ __forceinline__ void gload_lds16(const float* g, char* l) {
    __builtin_amdgcn_global_load_lds((const __attribute__((address_space(1))) void*)g,
                                     (__attribute__((address_space(3))) void*)l, 16, 0, 0);
}

// ===========================================================================
// setup_all: permute weights into MFMA-fragment order (fp16), fuse decoder.
// Fragment layout: frag[(g*16+ct)*8+ks][lane][8]:
//   value = W[j][k], j = g*256+ct*16+(lane&15), k = ks*32+(lane>>4)*8+e
// grid 1216 x 64 threads.
// ===========================================================================
__global__ void setup_all(const float* __restrict__ eWih, const float* __restrict__ eWhh,
                          const float* __restrict__ ebih, const float* __restrict__ ebhh,
                          const float* __restrict__ dWih, const float* __restrict__ dWhh,
                          const float* __restrict__ dbih, const float* __restrict__ dbhh,
                          const float* __restrict__ Wd,   const float* __restrict__ bd,
                          _Float16* __restrict__ W16E, _Float16* __restrict__ W16D,
                          _Float16* __restrict__ wihP, _Float16* __restrict__ wdP,
                          float* __restrict__ biasEP, float* __restrict__ biasDP)
{
    const int blk = blockIdx.x, l = threadIdx.x, p = l & 15, q = l >> 4;
    if (blk < 512) {                        // encoder Whh permute
        const int g = blk >> 7, ct = (blk >> 3) & 15, ks = blk & 7;
        const int j = g*256 + ct*16 + p, kb = ks*32 + q*8;
        _Float16* o = W16E + ((size_t)blk*64 + l)*8;
#pragma unroll
        for (int e = 0; e < 8; ++e) o[e] = (_Float16)eWhh[j*EE + kb + e];
    } else if (blk < 1024) {                // decoder fused W' = dWhh + dWih@Wd
        const int b2 = blk - 512;
        const int g = b2 >> 7, ct = (b2 >> 3) & 15, ks = b2 & 7;
        const int j = g*256 + ct*16 + p, kb = ks*32 + q*8;
        _Float16* o = W16D + ((size_t)b2*64 + l)*8;
#pragma unroll
        for (int e = 0; e < 8; ++e) {
            const int k = kb + e;
            float acc = dWhh[j*EE + k];
            for (int f = 0; f < FF; ++f) acc += dWih[j*FF + f] * Wd[f*EE + k];
            o[e] = (_Float16)acc;
        }
    } else if (blk < 1152) {                // encoder Wih permute (K=64: 2 k-slices)
        const int b2 = blk - 1024;
        const int g = b2 >> 5, ct = (b2 >> 1) & 15, k2 = b2 & 1;
        const int j = g*256 + ct*16 + p, kb = k2*32 + q*8;
        _Float16* o = wihP + ((size_t)b2*64 + l)*8;
#pragma unroll
        for (int e = 0; e < 8; ++e) o[e] = (_Float16)eWih[j*FF + kb + e];
    } else if (blk < 1184) {                // Wd permute for out-proj (4 n-tiles x 8 ks)
        const int b2 = blk - 1152;
        const int n = b2 >> 3, ks = b2 & 7;
        const int f = n*16 + p, kb = ks*32 + q*8;
        _Float16* o = wdP + ((size_t)b2*64 + l)*8;
#pragma unroll
        for (int e = 0; e < 8; ++e) o[e] = (_Float16)Wd[f*EE + kb + e];
    } else {                                // biases
        const int t2 = (blk - 1184)*64 + l;
        if (t2 < 1024) {
            biasEP[t2] = ebih[t2] + ebhh[t2];
        } else {
            const int j = t2 - 1024;
            float s = dbih[j] + dbhh[j];
            for (int f = 0; f < FF; ++f) s += dWih[j*FF + f] * bd[f];
            biasDP[j] = s;
        }
    }
}

// ===========================================================================
// lstm_main: 16 blocks x 512 threads (8 waves, 2/SIMD -> 256-VGPR budget).
// Block owns batch rows [16*bk,16*bk+16). Wave w owns e-cols [32w,32w+32)
// (ct0=2w, ct1=2w+1) for all 4 gates.
// Regs: i,f,g Whh/W' (48 frags = 192 VGPR). LDS: o-gate (128K) + h (8K) +
// x double-buffer (2x4K) = 147456 B. Wih loads stay in-loop (anti-LICM asm).
// 2-pass gates (i,f,g -> o); 2 barriers/step. Decoder h -> global Hbuf;
// out-proj is a separate fully-parallel kernel.
// ===========================================================================
__global__ __launch_bounds__(512, 2) void lstm_main(
    const float* __restrict__ x,
    const _Float16* __restrict__ W16E,
    const _Float16* __restrict__ W16D,
    const _Float16* __restrict__ wihP,
    const float* __restrict__ biasEP,
    const float* __restrict__ biasDP,
    _Float16* __restrict__ Hbuf)
{
    extern __shared__ char smem[];
    const f16x8* WO = (const f16x8*)smem;          // o-gate [16ct][8ks][64lane]
    _Float16* hb = (_Float16*)(smem + 131072);     // [16][256] fp16, XOR-swizzled
    float* xb0 = (float*)(smem + 139264);          // x tile [16][64] f32, swz
    float* xb1 = (float*)(smem + 143360);

    const int tid = threadIdx.x;
    const int w = tid >> 6, lane = tid & 63;
    const int p = lane & 15, q = lane >> 4;
    const int b0 = blockIdx.x << 4;
    const int ct0 = 2*w, ct1 = ct0 + 1;
    const int j0 = ct0*16 + p;

#define HA(ks) (*(const f16x8*)(hb + p*256 + (((ks)*32 + q*8) ^ ((p & 7) << 3))))

    // ---- init: stage o-slab (g=3) into LDS, zero h, stage x(0) ----
    {
        const f16x8* srcO = (const f16x8*)W16E + 3*128*64;
        f16x8* dst = (f16x8*)smem;
        for (int i = tid; i < 8192; i += 512) dst[i] = srcO[i];
        f16x8 z = {};
        ((f16x8*)hb)[tid] = z;
        if (w == 0) {
#pragma unroll
            for (int i = 0; i < 4; ++i) {
                const int row = 4*i + (lane >> 4);
                const int col = 4*((lane & 15) ^ (row & 7));   // T21 pre-swizzle
                gload_lds16(x + ((size_t)(b0 + row)*TT + 0)*FF + col,
                            (char*)xb0 + i*1024);
            }
        }
    }
    // ---- persistent register weights: gates i,f,g (encoder) ----
    f16x8 wi[2][8], wf[2][8], wg[2][8];
    {
        const f16x8* WF = (const f16x8*)W16E;
#pragma unroll
        for (int ks = 0; ks < 8; ++ks) {
            wi[0][ks] = WF[((0*16+ct0)*8+ks)*64 + lane];
            wi[1][ks] = WF[((0*16+ct1)*8+ks)*64 + lane];
            wf[0][ks] = WF[((1*16+ct0)*8+ks)*64 + lane];
            wf[1][ks] = WF[((1*16+ct1)*8+ks)*64 + lane];
            wg[0][ks] = WF[((2*16+ct0)*8+ks)*64 + lane];
            wg[1][ks] = WF[((2*16+ct1)*8+ks)*64 + lane];
        }
    }
    float biA[2], bfA[2], bgA[2], boA[2];
#pragma unroll
    for (int h = 0; h < 2; ++h) {
        biA[h] = biasEP[0*256 + j0 + 16*h];
        bfA[h] = biasEP[1*256 + j0 + 16*h];
        bgA[h] = biasEP[2*256 + j0 + 16*h];
        boA[h] = biasEP[3*256 + j0 + 16*h];
    }
    float cst[8];
#pragma unroll
    for (int r = 0; r < 8; ++r) cst[r] = 0.f;

    __syncthreads();   // weights + h0 + x(0) ready

    const f16x8* WIH = (const f16x8*)wihP;

    // ================= encoder: 1024 steps =================
    for (int t = 0; t < TT; ++t) {
        const float* xcur = (t & 1) ? xb1 : xb0;
        // x A-fragments (swizzled reads, 2-way bank-free)
        f32x4 v0 = *(const f32x4*)(xcur + p*64 + 4*(((2*q)  ) ^ (p & 7)));
        f32x4 v1 = *(const f32x4*)(xcur + p*64 + 4*(((2*q)+1) ^ (p & 7)));
        f32x4 v2 = *(const f32x4*)(xcur + p*64 + 4*(((2*q)+8) ^ (p & 7)));
        f32x4 v3 = *(const f32x4*)(xcur + p*64 + 4*(((2*q)+9) ^ (p & 7)));
        // stage x(t+1) a full step ahead (wave 0 only; drains at sync below)
        if (w == 0 && t + 1 < TT) {
            char* xnxt = (char*)(((t+1) & 1) ? xb1 : xb0);
#pragma unroll
            for (int i = 0; i < 4; ++i) {
                const int row = 4*i + (lane >> 4);
                const int col = 4*((lane & 15) ^ (row & 7));
                gload_lds16(x + ((size_t)(b0 + row)*TT + (t+1))*FF + col,
                            xnxt + i*1024);
            }
        }
        // keep Wih loads inside the loop (block LICM -> no 64-reg pin)
        const f16x8* WIHl = WIH;
        asm volatile("" : "+v"(WIHl));
        f16x8 xa0 = cvt2(v0, v1), xa1 = cvt2(v2, v3);

        // ---------- pass A: gates i, f, g (per column-half) ----------
#pragma unroll
        for (int h = 0; h < 2; ++h) {
            const int ct = ct0 + h;
            f16x8 ui0 = WIHl[((0*16+ct)*2+0)*64 + lane];
            f16x8 ui1 = WIHl[((0*16+ct)*2+1)*64 + lane];
            f16x8 uf0 = WIHl[((1*16+ct)*2+0)*64 + lane];
            f16x8 uf1 = WIHl[((1*16+ct)*2+1)*64 + lane];
            f16x8 ug0 = WIHl[((2*16+ct)*2+0)*64 + lane];
            f16x8 ug1 = WIHl[((2*16+ct)*2+1)*64 + lane];
            f32x4 AI = {0.f,0.f,0.f,0.f}, AF = AI, AG = AI;
#pragma unroll
            for (int ks = 0; ks < 8; ++ks) {
                f16x8 hk = HA(ks);
                AI = MFMA(hk, wi[h][ks], AI);
                AF = MFMA(hk, wf[h][ks], AF);
                AG = MFMA(hk, wg[h][ks], AG);
            }
            AI = MFMA(xa0, ui0, AI); AI = MFMA(xa1, ui1, AI);
            AF = MFMA(xa0, uf0, AF); AF = MFMA(xa1, uf1, AF);
            AG = MFMA(xa0, ug0, AG); AG = MFMA(xa1, ug1, AG);
#pragma unroll
            for (int r = 0; r < 4; ++r) {
                float I  = fsig(AI[r] + biA[h]);
                float Fv = fsig(AF[r] + bfA[h]);
                float G  = ftanhf(AG[r] + bgA[h]);
                cst[h*4+r] = Fv * cst[h*4+r] + I * G;
            }
        }
        // ---------- pass B: gate o + h update ----------
        {
            f16x8 uo0 = WIHl[((3*16+ct0)*2+0)*64 + lane];
            f16x8 uo1 = WIHl[((3*16+ct0)*2+1)*64 + lane];
            f16x8 uo2 = WIHl[((3*16+ct1)*2+0)*64 + lane];
            f16x8 uo3 = WIHl[((3*16+ct1)*2+1)*64 + lane];
            f32x4 O0 = {0.f,0.f,0.f,0.f}, O1 = O0;
#pragma unroll
            for (int ks = 0; ks < 8; ++ks) {
                f16x8 hk = HA(ks);
                O0 = MFMA(hk, WO[(ct0*8+ks)*64 + lane], O0);
                O1 = MFMA(hk, WO[(ct1*8+ks)*64 + lane], O1);
            }
            O0 = MFMA(xa0, uo0, O0); O0 = MFMA(xa1, uo1, O0);
            O1 = MFMA(xa0, uo2, O1); O1 = MFMA(xa1, uo3, O1);
            __syncthreads();   // all reads of h(t-1) done
#pragma unroll
            for (int r = 0; r < 4; ++r) {
                const int row = q*4 + r;
                float h0 = fsig(O0[r] + boA[0]) * ftanhf(cst[r]);
                float h1 = fsig(O1[r] + boA[1]) * ftanhf(cst[4+r]);
                hb[row*256 + ((ct0*16 + p) ^ ((row & 7) << 3))] = (_Float16)h0;
                hb[row*256 + ((ct1*16 + p) ^ ((row & 7) << 3))] = (_Float16)h1;
            }
            __syncthreads();   // h(t) + x(t+1) visible
        }
    }

    // ================= decoder transition =================
    {
        const f16x8* srcO = (const f16x8*)W16D + 3*128*64;
        f16x8* dst = (f16x8*)smem;
        for (int i = tid; i < 8192; i += 512) dst[i] = srcO[i];
        const f16x8* WF = (const f16x8*)W16D;
#pragma unroll
        for (int ks = 0; ks < 8; ++ks) {
            wi[0][ks] = WF[((0*16+ct0)*8+ks)*64 + lane];
            wi[1][ks] = WF[((0*16+ct1)*8+ks)*64 + lane];
            wf[0][ks] = WF[((1*16+ct0)*8+ks)*64 + lane];
            wf[1][ks] = WF[((1*16+ct1)*8+ks)*64 + lane];
            wg[0][ks] = WF[((2*16+ct0)*8+ks)*64 + lane];
            wg[1][ks] = WF[((2*16+ct1)*8+ks)*64 + lane];
        }
#pragma unroll
        for (int h = 0; h < 2; ++h) {
            biA[h] = biasDP[0*256 + j0 + 16*h];
            bfA[h] = biasDP[1*256 + j0 + 16*h];
            bgA[h] = biasDP[2*256 + j0 + 16*h];
            boA[h] = biasDP[3*256 + j0 + 16*h];
        }
        __syncthreads();
        // Hbuf[0] = encoder final h (unswizzle)
        const int row = tid >> 5, c8 = (tid & 31)*8;
        f16x8 hv = *(const f16x8*)(hb + row*256 + (c8 ^ ((row & 7) << 3)));
        *(f16x8*)(Hbuf + ((size_t)(b0 + row))*EE + c8) = hv;
    }

    // ================= decoder: 1023 steps =================
    for (int td = 1; td < TT; ++td) {
        // ---------- pass A ----------
#pragma unroll
        for (int h = 0; h < 2; ++h) {
            f32x4 AI = {0.f,0.f,0.f,0.f}, AF = AI, AG = AI;
#pragma unroll
            for (int ks = 0; ks < 8; ++ks) {
                f16x8 hk = HA(ks);
                AI = MFMA(hk, wi[h][ks], AI);
                AF = MFMA(hk, wf[h][ks], AF);
                AG = MFMA(hk, wg[h][ks], AG);
            }
#pragma unroll
            for (int r = 0; r < 4; ++r) {
                float I  = fsig(AI[r] + biA[h]);
                float Fv = fsig(AF[r] + bfA[h]);
                float G  = ftanhf(AG[r] + bgA[h]);
                cst[h*4+r] = Fv * cst[h*4+r] + I * G;
            }
        }
        // ---------- pass B ----------
        {
            f32x4 O0 = {0.f,0.f,0.f,0.f}, O1 = O0;
#pragma unroll
            for (int ks = 0; ks < 8; ++ks) {
                f16x8 hk = HA(ks);
                O0 = MFMA(hk, WO[(ct0*8+ks)*64 + lane], O0);
                O1 = MFMA(hk, WO[(ct1*8+ks)*64 + lane], O1);
            }
            __syncthreads();
#pragma unroll
            for (int r = 0; r < 4; ++r) {
                const int row = q*4 + r;
                float h0 = fsig(O0[r] + boA[0]) * ftanhf(cst[r]);
                float h1 = fsig(O1[r] + boA[1]) * ftanhf(cst[4+r]);
                hb[row*256 + ((ct0*16 + p) ^ ((row & 7) << 3))] = (_Float16)h0;
                hb[row*256 + ((ct1*16 + p) ^ ((row & 7) << 3))] = (_Float16)h1;
            }
            __syncthreads();
        }
        // stream h(td) to Hbuf (completion drains at next step's barrier)
        {
            const int row = tid >> 5, c8 = (tid & 31)*8;
            f16x8 hv = *(const f16x8*)(hb + row*256 + (c8 ^ ((row & 7) << 3)));
            *(f16x8*)(Hbuf + ((size_t)td*BB + b0 + row)*EE + c8) = hv;
        }
    }
#undef HA
}

// ===========================================================================
// out_proj: out[t][b][f] = Hbuf[t][b][:] @ Wd^T + bd.  Fully parallel.
// grid 16384 (t*16+bk) x 256 threads (4 waves, one 16-col n-tile each).
// ===========================================================================
__global__ __launch_bounds__(256) void out_proj(const _Float16* __restrict__ Hbuf,
                                                const _Float16* __restrict__ wdP,
                                                const float* __restrict__ bd,
                                                float* __restrict__ out)
{
    const int blk = blockIdx.x, t = blk >> 4, bk = blk & 15;
    const int tid = threadIdx.x, n = tid >> 6, lane = tid & 63;
    const int p = lane & 15, q = lane >> 4;
    const _Float16* hrow = Hbuf + ((size_t)t*BB + bk*16 + p)*EE;
    const f16x8* WDP = (const f16x8*)wdP;
    float b = bd[n*16 + p];
    f32x4 acc = {b, b, b, b};
#pragma unroll
    for (int ks = 0; ks < 8; ++ks) {
        f16x8 a = *(const f16x8*)(hrow + ks*32 + q*8);
        f16x8 wv = WDP[(n*8 + ks)*64 + lane];
        acc = MFMA(a, wv, acc);
    }
    float* ob = out + ((size_t)t*BB + bk*16)*FF + n*16 + p;
#pragma unroll
    for (int r = 0; r < 4; ++r) ob[(q*4 + r)*FF] = acc[r];
}

// ===========================================================================
// Fallback path (round-0 kernel, verified-passing, slow) if ws too small.
// ===========================================================================
__global__ void setup_fb(const float* __restrict__ eWih, const float* __restrict__ eWhh,
                         const float* __restrict__ ebih, const float* __restrict__ ebhh,
                         const float* __restrict__ dWih, const float* __restrict__ dWhh,
                         const float* __restrict__ dbih, const float* __restrict__ dbhh,
                         const float* __restrict__ Wd,   const float* __restrict__ bd,
                         _Float16* __restrict__ whh16, _Float16* __restrict__ wp16,
                         _Float16* __restrict__ wih16, _Float16* __restrict__ wd16,
                         float* __restrict__ biasE, float* __restrict__ biasD)
{
    const int j = blockIdx.x, e = threadIdx.x;
    __shared__ float lih[FF];
    if (e < FF) lih[e] = dWih[j*FF + e];
    __syncthreads();
    float acc = dWhh[j*EE + e];
    for (int f = 0; f < FF; ++f) acc += lih[f] * Wd[f*EE + e];
    wp16[j*EE + e]  = (_Float16)acc;
    whh16[j*EE + e] = (_Float16)eWhh[j*EE + e];
    if (e < FF) wih16[j*FF + e] = (_Float16)eWih[j*FF + e];
    if (j < FF) wd16[j*EE + e]  = (_Float16)Wd[j*EE + e];
    if (e == 0) {
        float s = dbih[j] + dbhh[j];
        for (int f = 0; f < FF; ++f) s += lih[f] * bd[f];
        biasD[j] = s; biasE[j] = ebih[j] + ebhh[j];
    }
}

__global__ __launch_bounds__(1024, 4) void lstm_fb(
    const float* __restrict__ x, const _Float16* __restrict__ whhG,
    const _Float16* __restrict__ wpG, const _Float16* __restrict__ wihG,
    const _Float16* __restrict__ wdG, const float* __restrict__ biasE,
    const float* __restrict__ biasD, const float* __restrict__ bdp,
    float* __restrict__ out)
{
    const int tid = threadIdx.x, w = tid >> 6, lane = tid & 63;
    const int p = lane & 15, q = lane >> 4, b0 = blockIdx.x << 4;
    __shared__ _Float16 hbuf[2][16*256];
    f16x8 wgt[4][8]; f16x8 wih[4][2]; float be[4], bp[4];
#pragma unroll
    for (int g = 0; g < 4; ++g) {
        const int j = g*256 + w*16 + p;
#pragma unroll
        for (int ks = 0; ks < 8; ++ks) wgt[g][ks] = *(const f16x8*)(whhG + j*EE + ks*32 + q*8);
        wih[g][0] = *(const f16x8*)(wihG + j*FF + q*8);
        wih[g][1] = *(const f16x8*)(wihG + j*FF + 32 + q*8);
        be[g] = biasE[j]; bp[g] = biasD[j];
    }
    f16x8 ha[8] = {}; f32x4 cst = {0.f,0.f,0.f,0.f};
    const float* xb = x + (size_t)(b0 + p)*TT*FF;
    f32x4 r0 = *(const f32x4*)(xb + q*8), r1 = *(const f32x4*)(xb + q*8 + 4);
    f32x4 r2 = *(const f32x4*)(xb + 32 + q*8), r3 = *(const f32x4*)(xb + 32 + q*8 + 4);
    for (int t = 0; t < TT; ++t) {
        f16x8 xa0 = cvt2(r0, r1), xa1 = cvt2(r2, r3);
        f32x4 a0 = {be[0],be[0],be[0],be[0]}, a1 = {be[1],be[1],be[1],be[1]};
        f32x4 a2 = {be[2],be[2],be[2],be[2]}, a3 = {be[3],be[3],be[3],be[3]};
#pragma unroll
        for (int ks = 0; ks < 8; ++ks) {
            a0 = MFMA(ha[ks], wgt[0][ks], a0); a1 = MFMA(ha[ks], wgt[1][ks], a1);
            a2 = MFMA(ha[ks], wgt[2][ks], a2); a3 = MFMA(ha[ks], wgt[3][ks], a3);
        }
        a0 = MFMA(xa0, wih[0][0], a0); a0 = MFMA(xa1, wih[0][1], a0);
        a1 = MFMA(xa0, wih[1][0], a1); a1 = MFMA(xa1, wih[1][1], a1);
        a2 = MFMA(xa0, wih[2][0], a2); a2 = MFMA(xa1, wih[2][1], a2);
        a3 = MFMA(xa0, wih[3][0], a3); a3 = MFMA(xa1, wih[3][1], a3);
        if (t + 1 < TT) {
            const float* xn = xb + (size_t)(t+1)*FF;
            r0 = *(const f32x4*)(xn + q*8); r1 = *(const f32x4*)(xn + q*8 + 4);
            r2 = *(const f32x4*)(xn + 32 + q*8); r3 = *(const f32x4*)(xn + 32 + q*8 + 4);
        }
#pragma unroll
        for (int r = 0; r < 4; ++r) {
            float ivv = fsig(a0[r]), fvv = fsig(a1[r]), gv = ftanhf(a2[r]), ov = fsig(a3[r]);
            float c = fvv*cst[r] + ivv*gv; cst[r] = c;
            float hv = ov*ftanhf(c);
            const int row = q*4 + r;
            hbuf[t&1][row*256 + ((w*16+p) ^ ((row&7)<<3))] = (_Float16)hv;
        }
        __syncthreads();
        {
            const _Float16* hbp = hbuf[t&1];
#pragma unroll
            for (int ks = 0; ks < 8; ++ks)
                ha[ks] = *(const f16x8*)(hbp + p*256 + ((ks*32 + q*8) ^ ((p&7)<<3)));
        }
    }
#pragma unroll
    for (int g = 0; g < 4; ++g) {
        const int j = g*256 + w*16 + p;
#pragma unroll
        for (int ks = 0; ks < 8; ++ks) wgt[g][ks] = *(const f16x8*)(wpG + j*EE + ks*32 + q*8);
    }
    f16x8 wd[8] = {}; float bdv = 0.f;
    if (w < 4) {
#pragma unroll
        for (int ks = 0; ks < 8; ++ks) wd[ks] = *(const f16x8*)(wdG + (w*16+p)*EE + ks*32 + q*8);
        bdv = bdp[w*16 + p];
    }
    for (int t = 0; t < TT; ++t) {
        if (w < 4) {
            f32x4 oa = {bdv,bdv,bdv,bdv};
#pragma unroll
            for (int ks = 0; ks < 8; ++ks) oa = MFMA(ha[ks], wd[ks], oa);
            float* ob = out + (size_t)t*(BB*FF) + (size_t)b0*FF + (w*16 + p);
#pragma unroll
            for (int r = 0; r < 4; ++r) ob[(q*4 + r)*FF] = oa[r];
        }
        if (t == TT-1) break;
        f32x4 a0 = {bp[0],bp[0],bp[0],bp[0]}, a1 = {bp[1],bp[1],bp[1],bp[1]};
        f32x4 a2 = {bp[2],bp[2],bp[2],bp[2]}, a3 = {bp[3],bp[3],bp[3],bp[3]};
#pragma unroll
        for (int ks = 0; ks < 8; ++ks) {
            a0 = MFMA(ha[ks], wgt[0][ks], a0); a1 = MFMA(ha[ks], wgt[1][ks], a1);
            a2 = MFMA(ha[ks], wgt[2][ks], a2); a3 = MFMA(ha[ks], wgt[3][ks], a3);
        }
#pragma unroll
        for (int r = 0; r < 4; ++r) {
            float ivv = fsig(a0[r]), fvv = fsig(a1[r]), gv = ftanhf(a2[r]), ov = fsig(a3[r]);
            float c = fvv*cst[r] + ivv*gv; cst[r] = c;
            float hv = ov*ftanhf(c);
            const int row = q*4 + r;
            hbuf[t&1][row*256 + ((w*16+p) ^ ((row&7)<<3))] = (_Float16)hv;
        }
        __syncthreads();
        {
            const _Float16* hbp = hbuf[t&1];
#pragma unroll
            for (int ks = 0; ks < 8; ++ks)
                ha[ks] = *(const f16x8*)(hbp + p*256 + ((ks*32 + q*8) ^ ((p&7)<<3)));
        }
    }
}

// ---------------------------------------------------------------------------
extern "C" void kernel_launch(void* const* d_in, const int* in_sizes, int n_in,
                              void* d_out, int out_size, void* d_ws, size_t ws_size,
                              hipStream_t stream) {
    const float* x    = (const float*)d_in[0];
    const float* eWih = (const float*)d_in[1];
    const float* eWhh = (const float*)d_in[2];
    const float* ebih = (const float*)d_in[3];
    const float* ebhh = (const float*)d_in[4];
    const float* dWih = (const float*)d_in[5];
    const float* dWhh = (const float*)d_in[6];
    const float* dbih = (const float*)d_in[7];
    const float* dbhh = (const float*)d_in[8];
    const float* Wd   = (const float*)d_in[9];
    const float* bd   = (const float*)d_in[10];

    const size_t NEED = 2097152ull + 134217728ull;   // tables + Hbuf
    if (ws_size >= NEED) {
        char* ws = (char*)d_ws;
        _Float16* W16E  = (_Float16*)(ws + 0);        // 512 KB
        _Float16* W16D  = (_Float16*)(ws + 524288);   // 512 KB
        _Float16* wihP  = (_Float16*)(ws + 1048576);  // 128 KB
        _Float16* wdP   = (_Float16*)(ws + 1179648);  // 32 KB
        float*    biasEP = (float*)(ws + 1212416);    // 4 KB
        float*    biasDP = (float*)(ws + 1216512);    // 4 KB
        _Float16* Hbuf  = (_Float16*)(ws + 2097152);  // 128 MB

        hipLaunchKernelGGL(setup_all, dim3(1216), dim3(64), 0, stream,
                           eWih, eWhh, ebih, ebhh, dWih, dWhh, dbih, dbhh, Wd, bd,
                           W16E, W16D, wihP, wdP, biasEP, biasDP);

        hipFuncSetAttribute(reinterpret_cast<const void*>(lstm_main),
                            hipFuncAttributeMaxDynamicSharedMemorySize, 147456);
        hipLaunchKernelGGL(lstm_main, dim3(16), dim3(512), 147456, stream,
                           x, W16E, W16D, wihP, biasEP, biasDP, Hbuf);

        hipLaunchKernelGGL(out_proj, dim3(16384), dim3(256), 0, stream,
                           Hbuf, wdP, bd, (float*)d_out);
    } else {
        char* ws = (char*)d_ws;
        _Float16* whh16 = (_Float16*)(ws + 0);
        _Float16* wp16  = (_Float16*)(ws + 524288);
        _Float16* wih16 = (_Float16*)(ws + 1048576);
        _Float16* wd16  = (_Float16*)(ws + 1179648);
        float*    biasE = (float*)(ws + 1212416);
        float*    biasD = (float*)(ws + 1216512);
        hipLaunchKernelGGL(setup_fb, dim3(1024), dim3(256), 0, stream,
                           eWih, eWhh, ebih, ebhh, dWih, dWhh, dbih, dbhh, Wd, bd,
                           whh16, wp16, wih16, wd16, biasE, biasD);
        hipLaunchKernelGGL(lstm_fb, dim3(16), dim3(1024), 0, stream,
                           x, whh16, wp16, wih16, wd16, biasE, biasD, bd, (float*)d_out);
    }
}